// Round 9
// baseline (225.716 us; speedup 1.0000x reference)
//
#include <hip/hip_runtime.h>

// BinaryTreeShConv on MI355X (gfx950) — R8: DIAGNOSTIC ROUND.
// Real computation = R1 structure (prep + fused, 40.3 us, absmax 0.25).
// Plus 3 probe kernels (write only to d_ws) isolating the three memory
// access patterns; read their per-dispatch dur/counters from rocprof:
//   P1 probe_stream : ck as coalesced dwordx4, 6 full passes (805 MB)
//   P2 probe_ushort : ck hi-ushort strided exactly like R1 stage A, 5 passes
//   P3 probe_gather : idx -> sig gather exactly like R1 stage A, 8 passes

typedef __attribute__((ext_vector_type(8))) short bf16x8;
typedef __attribute__((ext_vector_type(16))) float f32x16;
typedef __attribute__((ext_vector_type(4))) float f32x4;

__device__ __forceinline__ unsigned short f2bf_rne(float f) {
    union { float f; unsigned int u; } x;
    x.f = f;
    unsigned int u = x.u;
    return (unsigned short)((u + 0x7fffu + ((u >> 16) & 1u)) >> 16);
}
__device__ __forceinline__ unsigned short f2bf_rh(float f) {  // round-half-up
    union { float f; unsigned int u; } x;
    x.f = f;
    return (unsigned short)((x.u + 0x8000u) >> 16);
}

// ---------------- R1 prep (unchanged) ----------------
__global__ __launch_bounds__(256) void prep_kernel(
        const float* __restrict__ W, const float* __restrict__ sig,
        unsigned short* __restrict__ Wf, unsigned short* __restrict__ sigbf) {
    int tid = blockIdx.x * 256 + threadIdx.x;
    if (tid < 32768) {
        int j = tid & 7;
        int l = (tid >> 3) & 63;
        int pair = tid >> 9;
        int s = pair >> 1;
        int t = pair & 1;
        int i = 16 * t + (l & 15);
        int crn = 32 * s + 8 * (l >> 4) + j;
        Wf[tid] = f2bf_rne(W[i * 1024 + crn]);
    } else {
        int e = (tid - 32768) * 8;
        if (e < 8 * 4096 * 32) {
            f32x4 a = *(const f32x4*)(sig + e);
            f32x4 b = *(const f32x4*)(sig + e + 4);
            bf16x8 v;
            v[0] = (short)f2bf_rne(a[0]); v[1] = (short)f2bf_rne(a[1]);
            v[2] = (short)f2bf_rne(a[2]); v[3] = (short)f2bf_rne(a[3]);
            v[4] = (short)f2bf_rne(b[0]); v[5] = (short)f2bf_rne(b[1]);
            v[6] = (short)f2bf_rne(b[2]); v[7] = (short)f2bf_rne(b[3]);
            *(bf16x8*)(sigbf + e) = v;
        }
    }
}

// ---------------- R1 fused (unchanged, 40.3 us) ----------------
__global__ __launch_bounds__(256) void fused_kernel(
        const unsigned short* __restrict__ sigbf, const int* __restrict__ pidx,
        const float* __restrict__ ck, const unsigned short* __restrict__ Wf,
        const float* __restrict__ bias, float* __restrict__ out) {
    __shared__ __align__(16) unsigned short T_lds[16 * 1032];
    const int tid = threadIdx.x;
    const int l = tid & 63;
    const int w = tid >> 6;
    const int m0 = blockIdx.x * 16;
    const int b = m0 >> 12;
    const int cc = l & 31;
    const int g = l >> 5;
    const unsigned short* sgb = sigbf + (size_t)b * (4096 * 32);
    const unsigned short* ckh = (const unsigned short*)ck;

    for (int q = 0; q < 4; ++q) {
        const int bvl = w * 4 + q;
        const int m = m0 + bvl;
        const int* idxp = pidx + (size_t)m * 32;
        const size_t kbase = (size_t)m * 1024;
        f32x16 acc = {};
        #pragma unroll
        for (int half = 0; half < 2; ++half) {
            bf16x8 af, bfr;
            #pragma unroll
            for (int j = 0; j < 8; ++j) {
                const int p = half * 16 + 8 * g + j;
                const int row = idxp[p];
                af[j]  = (short)sgb[row * 32 + cc];
                bfr[j] = (short)ckh[((kbase + p * 32 + cc) << 1) | 1];
            }
            acc = __builtin_amdgcn_mfma_f32_32x32x16_bf16(af, bfr, acc, 0, 0, 0);
        }
        unsigned short* trow = T_lds + bvl * 1032 + cc + g * 128;
        #pragma unroll
        for (int r = 0; r < 16; ++r) {
            const int ct = (r & 3) + 8 * (r >> 2);
            trow[ct * 32] = f2bf_rh(acc[r]);
        }
    }
    __syncthreads();

    f32x4 acc0 = {}, acc1 = {};
    const int lg = l >> 4;
    const int ln = l & 15;
    #pragma unroll
    for (int si = 0; si < 8; ++si) {
        const int s = 8 * w + si;
        const bf16x8 af = *(const bf16x8*)(T_lds + ln * 1032 + s * 32 + 8 * lg);
        const bf16x8* wrow = (const bf16x8*)(Wf + (size_t)(s * 2) * 512);
        const bf16x8 b0 = wrow[l];
        const bf16x8 b1 = wrow[64 + l];
        acc0 = __builtin_amdgcn_mfma_f32_16x16x32_bf16(af, b0, acc0, 0, 0, 0);
        acc1 = __builtin_amdgcn_mfma_f32_16x16x32_bf16(af, b1, acc1, 0, 0, 0);
    }
    __syncthreads();

    float* red = (float*)T_lds;
    {
        f32x4* rp = (f32x4*)(red + w * 512);
        rp[l]      = acc0;
        rp[64 + l] = acc1;
    }
    __syncthreads();

    #pragma unroll
    for (int o0 = 0; o0 < 2; ++o0) {
        const int o = o0 * 256 + tid;
        float sum = red[o] + red[512 + o] + red[1024 + o] + red[1536 + o];
        const int t  = o >> 8;
        const int ll = (o >> 2) & 63;
        const int r  = o & 3;
        const int bv = ((ll >> 4) << 2) + r;
        const int i  = 16 * t + (ll & 15);
        sum += bias[i];
        out[(size_t)(m0 + bv) * 32 + i] = sum > 0.f ? sum : 0.f;
    }
}

// ---------------- P1: coalesced dwordx4 stream over ck ----------------
// ck = 8,388,608 f32x4 = 16 chunks x 524,288. 6 rotated full passes.
__global__ __launch_bounds__(256, 2) void probe_stream(
        const float* __restrict__ ck, float* __restrict__ sink) {
    const int t = blockIdx.x * 256 + threadIdx.x;     // 0..524287
    const f32x4* ckv = (const f32x4*)ck;
    float acc = 0.f;
    for (int pass = 0; pass < 6; ++pass) {
        #pragma unroll
        for (int i = 0; i < 16; ++i) {
            const int chunk = (i + pass) & 15;
            f32x4 v = ckv[(size_t)chunk * 524288 + t];
            acc += v[0] + v[1] + v[2] + v[3];
        }
    }
    sink[t] = acc;
}

// ---------------- P2: hi-ushort strided ck, exact R1 pattern ----------------
__global__ __launch_bounds__(256, 2) void probe_ushort(
        const float* __restrict__ ck, unsigned int* __restrict__ sink) {
    const int tid = threadIdx.x;
    const int l = tid & 63;
    const int w = tid >> 6;
    const int cc = l & 31;
    const int g = l >> 5;
    const unsigned short* ckh = (const unsigned short*)ck;
    unsigned int acc = 0;
    for (int pass = 0; pass < 5; ++pass) {
        const int mb = (int)(((blockIdx.x + pass * 409u) & 2047u) * 16) + w * 4;
        for (int q = 0; q < 4; ++q) {
            const size_t kbase = (size_t)(mb + q) * 1024;
            #pragma unroll
            for (int h = 0; h < 2; ++h) {
                #pragma unroll
                for (int j = 0; j < 8; ++j) {
                    const int p = h * 16 + 8 * g + j;
                    acc += ckh[((kbase + p * 32 + cc) << 1) | 1];
                }
            }
        }
    }
    sink[blockIdx.x * 256 + tid] = acc;
}

// ---------------- P3: idx -> sig gather, exact R1 pattern ----------------
__global__ __launch_bounds__(256, 2) void probe_gather(
        const float* __restrict__ sig, const int* __restrict__ pidx,
        float* __restrict__ sink) {
    const int tid = threadIdx.x;
    const int l = tid & 63;
    const int w = tid >> 6;
    const int cc = l & 31;
    const int g = l >> 5;
    float acc = 0.f;
    for (int pass = 0; pass < 8; ++pass) {
        const int m0 = (int)(((blockIdx.x + pass * 257u) & 2047u) * 16);
        for (int q = 0; q < 4; ++q) {
            const int m = m0 + w * 4 + q;
            const int b = m >> 12;
            const int* idxp = pidx + (size_t)m * 32;
            const float* sgb = sig + ((size_t)b << 12) * 32;
            #pragma unroll
            for (int h = 0; h < 2; ++h) {
                #pragma unroll
                for (int j = 0; j < 8; ++j) {
                    const int p = h * 16 + 8 * g + j;
                    const int row = idxp[p];
                    acc += sgb[row * 32 + cc];
                }
            }
        }
    }
    sink[blockIdx.x * 256 + tid] = acc;
}

extern "C" void kernel_launch(void* const* d_in, const int* in_sizes, int n_in,
                              void* d_out, int out_size, void* d_ws, size_t ws_size,
                              hipStream_t stream) {
    const float* sig  = (const float*)d_in[0];
    const int*   pidx = (const int*)d_in[1];
    const float* ck   = (const float*)d_in[2];
    const float* W    = (const float*)d_in[3];
    const float* bias = (const float*)d_in[4];
    float* out = (float*)d_out;
    unsigned short* Wf    = (unsigned short*)d_ws;           // 64 KB
    unsigned short* sigbf = Wf + 32768;                      // 2 MB
    char* base = (char*)d_ws + (64 << 10) + (2 << 20);
    float*        sink1 = (float*)base;                      // 2 MB
    unsigned int* sink2 = (unsigned int*)(base + (2 << 20)); // 2 MB
    float*        sink3 = (float*)(base + (4 << 20));        // 2 MB

    // Real computation (R1, proven):
    prep_kernel<<<640, 256, 0, stream>>>(W, sig, Wf, sigbf);
    fused_kernel<<<2048, 256, 0, stream>>>(sigbf, pidx, ck, Wf, bias, out);

    // Diagnostic probes (write only to d_ws):
    probe_stream<<<2048, 256, 0, stream>>>(ck, sink1);
    probe_ushort<<<2048, 256, 0, stream>>>(ck, sink2);
    probe_gather<<<2048, 256, 0, stream>>>(sig, pidx, sink3);
}

// Round 10
// 38.845 us; speedup vs baseline: 5.8107x; 5.8107x over previous
//
#include <hip/hip_runtime.h>

// BinaryTreeShConv on MI355X (gfx950).
// out[b,v,i] = relu(bias[i] + sum_{p,c,rn} W[i,c,rn] * K[b,v,p,rn] * sig[b, idx[b,v,p], c])
// B=8 V=4096 P=32 C=32 RN=32 OUT=32, CRN=1024.
//
// R9: phase-separated streaming (informed by R8 probes: each access pattern
// standalone hits ~6.7 TB/s line traffic; the fused interleave was the wall).
//  - Phase 0 (pure streaming, probe-like): all ck f32x4 staging loads + all
//    sig gathers issued back-to-back; idx via wave-uniform scalar loads;
//    ck packed to bf16 in LDS [bv][p][rn].
//  - Phase A: MFMA stage A from LDS + registers only.
//  - Phase B: k-split stage B (R1 structure) + reduce + epilogue.
//  - 4 waves / 8 bv / 32.7 KB LDS -> 4 blocks/CU (16 waves), grid 4096.
// Numerics identical to R1 (absmax 0.25): ck hi-ushort truncate, sigbf RNE,
// Wf RNE, T round-half-up.

typedef __attribute__((ext_vector_type(8))) short bf16x8;
typedef __attribute__((ext_vector_type(4))) short short4v;
typedef __attribute__((ext_vector_type(16))) float f32x16;
typedef __attribute__((ext_vector_type(4))) float f32x4;

__device__ __forceinline__ unsigned short f2bf_rne(float f) {
    union { float f; unsigned int u; } x;
    x.f = f;
    unsigned int u = x.u;
    return (unsigned short)((u + 0x7fffu + ((u >> 16) & 1u)) >> 16);
}
__device__ __forceinline__ unsigned short f2bf_rh(float f) {  // round-half-up
    union { float f; unsigned int u; } x;
    x.f = f;
    return (unsigned short)((x.u + 0x8000u) >> 16);
}

// ---------------- prep: Wf fragment pack + sig -> bf16 (unchanged) ----------------
__global__ __launch_bounds__(256) void prep_kernel(
        const float* __restrict__ W, const float* __restrict__ sig,
        unsigned short* __restrict__ Wf, unsigned short* __restrict__ sigbf) {
    int tid = blockIdx.x * 256 + threadIdx.x;
    if (tid < 32768) {
        int j = tid & 7;
        int l = (tid >> 3) & 63;
        int pair = tid >> 9;                    // s*2 + t
        int s = pair >> 1;
        int t = pair & 1;
        int i = 16 * t + (l & 15);
        int crn = 32 * s + 8 * (l >> 4) + j;
        Wf[tid] = f2bf_rne(W[i * 1024 + crn]);
    } else {
        int e = (tid - 32768) * 8;              // sig has 1,048,576 elements
        if (e < 8 * 4096 * 32) {
            f32x4 a = *(const f32x4*)(sig + e);
            f32x4 b = *(const f32x4*)(sig + e + 4);
            bf16x8 v;
            v[0] = (short)f2bf_rne(a[0]); v[1] = (short)f2bf_rne(a[1]);
            v[2] = (short)f2bf_rne(a[2]); v[3] = (short)f2bf_rne(a[3]);
            v[4] = (short)f2bf_rne(b[0]); v[5] = (short)f2bf_rne(b[1]);
            v[6] = (short)f2bf_rne(b[2]); v[7] = (short)f2bf_rne(b[3]);
            *(bf16x8*)(sigbf + e) = v;
        }
    }
}

__global__ __launch_bounds__(256, 4) void fused_kernel(
        const unsigned short* __restrict__ sigbf, const int* __restrict__ pidx,
        const float* __restrict__ ck, const unsigned short* __restrict__ Wf,
        const float* __restrict__ bias, float* __restrict__ out) {
    __shared__ __align__(16) unsigned short ckb[8 * 1024];   // 16,384 B [bv][p][rn]
    __shared__ __align__(16) unsigned short T_lds[8 * 1032]; // 16,512 B
    const int tid = threadIdx.x;
    const int l = tid & 63;
    const int g = l >> 5;
    const int cc = l & 31;
    const int wu = __builtin_amdgcn_readfirstlane(tid >> 6);  // wave 0..3, SGPR
    const int m0 = blockIdx.x * 8;   // 8 bv per block (same b)
    const int b = m0 >> 12;
    const unsigned short* sgb = sigbf + (size_t)b * (4096 * 32);

    // ======== Phase 0: pure streaming (probe-like instruction mix) ========
    // (a) ck staging: 8 bv x 4 KB = 32 KB, 8 f32x4 per thread, all issued up front
    f32x4 st[8];
    {
        const f32x4* ckv = (const f32x4*)(ck + (size_t)m0 * 1024);
        #pragma unroll
        for (int i = 0; i < 8; ++i) st[i] = ckv[i * 256 + tid];
    }
    // (b) idx for this wave's 2 bv: wave-uniform scalar loads (64 ints -> SGPRs)
    int rows[64];
    {
        const int* idxp = pidx + (size_t)(m0 + 2 * wu) * 32;
        #pragma unroll
        for (int k = 0; k < 64; ++k) rows[k] = idxp[k];
    }
    // (c) gathers: 32 per lane (2 bv x 16), addresses = cndmask(row_g0,row_g1)
    unsigned short ga[32];
    #pragma unroll
    for (int q = 0; q < 2; ++q) {
        #pragma unroll
        for (int h = 0; h < 2; ++h) {
            #pragma unroll
            for (int j = 0; j < 8; ++j) {
                const int rlo = rows[q * 32 + h * 16 + j];
                const int rhi = rows[q * 32 + h * 16 + 8 + j];
                const int row = g ? rhi : rlo;
                ga[q * 16 + h * 8 + j] = sgb[row * 32 + cc];
            }
        }
    }
    // (d) pack ck staging to bf16 and write LDS (linear, coalesced b64)
    #pragma unroll
    for (int i = 0; i < 8; ++i) {
        union { f32x4 f; unsigned int u[4]; } x;
        x.f = st[i];
        short4v v = { (short)(x.u[0] >> 16), (short)(x.u[1] >> 16),
                      (short)(x.u[2] >> 16), (short)(x.u[3] >> 16) };
        *(short4v*)(ckb + (i * 256 + tid) * 4) = v;
    }
    __syncthreads();

    // ======== Phase A: stage-A MFMA (LDS + regs only) ========
    // wave wu owns bv_local = 2wu, 2wu+1
    #pragma unroll
    for (int q = 0; q < 2; ++q) {
        const unsigned short* ct = ckb + (2 * wu + q) * 1024;   // [32p][32rn]
        f32x16 acc = {};
        #pragma unroll
        for (int h = 0; h < 2; ++h) {
            bf16x8 af, bfr;
            #pragma unroll
            for (int j = 0; j < 8; ++j) {
                const int p = h * 16 + 8 * g + j;
                af[j]  = (short)ga[q * 16 + h * 8 + j];
                bfr[j] = (short)ct[p * 32 + cc];
            }
            acc = __builtin_amdgcn_mfma_f32_32x32x16_bf16(af, bfr, acc, 0, 0, 0);
        }
        // D map (verified): col=cc, row=(r&3)+8*(r>>2)+4*g ; T[c][rn] bf16
        unsigned short* trow = T_lds + (2 * wu + q) * 1032 + cc + g * 128;
        #pragma unroll
        for (int r = 0; r < 16; ++r)
            trow[((r & 3) + 8 * (r >> 2)) * 32] = f2bf_rh(acc[r]);
    }
    __syncthreads();

    // ======== Phase B: stage B, k-split s = 8w..8w+7, both i-tiles ========
    // A-frag row ln: T row (ln&7) — rows 8-15 duplicate 0-7 (same LDS addr,
    // broadcast, conflict-free); their D rows are discarded.
    f32x4 acc0 = {}, acc1 = {};
    const int lg = l >> 4;
    const int ln = l & 15;
    #pragma unroll
    for (int si = 0; si < 8; ++si) {
        const int s = 8 * wu + si;
        const bf16x8 af = *(const bf16x8*)(T_lds + (ln & 7) * 1032 + s * 32 + 8 * lg);
        const bf16x8* wrow = (const bf16x8*)(Wf + (size_t)(s * 2) * 512);
        const bf16x8 b0 = wrow[l];        // pair 2s+0, coalesced 16B/lane, L2-hot
        const bf16x8 b1 = wrow[64 + l];   // pair 2s+1
        acc0 = __builtin_amdgcn_mfma_f32_16x16x32_bf16(af, b0, acc0, 0, 0, 0);
        acc1 = __builtin_amdgcn_mfma_f32_16x16x32_bf16(af, b1, acc1, 0, 0, 0);
    }
    __syncthreads();                      // T reads done; reuse T_lds as f32 red

    float* red = (float*)T_lds;           // 4 waves * 2 tiles * 256 f32 = 8 KB
    {
        f32x4* rp = (f32x4*)(red + wu * 512);
        rp[l]      = acc0;                // [w][t=0][l][r]
        rp[64 + l] = acc1;                // [w][t=1][l][r]
    }
    __syncthreads();

    // 256 outputs: thread tid -> (bv = tid>>5, i = tid&31).
    // D map: row = lg*4 + r = bv (valid 0-7), col = ln = i&15, tile t = i>>4.
    {
        const int bv  = tid >> 5;
        const int i   = tid & 31;
        const int t   = i >> 4;
        const int col = i & 15;
        const int lgi = bv >> 2;          // 0..1
        const int r   = bv & 3;
        const int li  = lgi * 16 + col;
        const int o   = t * 256 + li * 4 + r;
        float sum = red[o] + red[512 + o] + red[1024 + o] + red[1536 + o];
        sum += bias[i];
        out[(size_t)(m0 + bv) * 32 + i] = sum > 0.f ? sum : 0.f;
    }
}

extern "C" void kernel_launch(void* const* d_in, const int* in_sizes, int n_in,
                              void* d_out, int out_size, void* d_ws, size_t ws_size,
                              hipStream_t stream) {
    const float* sig  = (const float*)d_in[0];
    const int*   pidx = (const int*)d_in[1];
    const float* ck   = (const float*)d_in[2];
    const float* W    = (const float*)d_in[3];
    const float* bias = (const float*)d_in[4];
    float* out = (float*)d_out;
    unsigned short* Wf    = (unsigned short*)d_ws;       // 64 KB fragment-ordered W
    unsigned short* sigbf = Wf + 32768;                  // 2 MB bf16 signal

    prep_kernel<<<640, 256, 0, stream>>>(W, sig, Wf, sigbf);
    fused_kernel<<<4096, 256, 0, stream>>>(sigbf, pidx, ck, Wf, bias, out);
}